// Round 4
// baseline (237.260 us; speedup 1.0000x reference)
//
#include <hip/hip_runtime.h>
#include <hip/hip_bf16.h>

// GCN 3-layer forward on MI355X.  (R14: 8-deep gather MLP)
// h' = bf16( dinv .* (x @ W) );  out = relu(dinv .* (h'[i]+sum h'[src]) + b)
// CSR via single-pass bucket binning (arena slots); neighbor lists padded to
// 4-entry alignment with DUMMY index n (points at a zeroed row in each
// h-buffer) -> gather loops are pure int4 groups.
// Gather phases: fused64 16 lanes/node (R10-measured optimum), fused32 8,
// agg3 4.  fused64/fused32 inner loops unrolled to 8 rows in flight
// (2 int4 index loads + 8 uint4 row loads issued before any accumulate):
// halves the serialized latency exposures per node (latency-bound regime,
// no pipe >50% in R11-R13 counters).
// Dense gemms on mfma_f32_16x16x32_bf16 with split-bf16 (hi + residual lo)
// on both operands (~fp32 product precision).
// R12 post-mortem: persistent grids regress (tail quantization); per-tile
// grids.  FETCH ~83MB is compulsory per-XCD traffic; not reducible.

#define BLOCK 256
#define NBUCKET 512
#define CHUNK 4096
#define SLOT 4608
#define MAX_NPB 256

typedef float f32x4 __attribute__((ext_vector_type(4)));
typedef short bf16x8 __attribute__((ext_vector_type(8)));

__device__ __forceinline__ unsigned int bf16r(float f) {
  unsigned int u = __float_as_uint(f);
  u += 0x7fffu + ((u >> 16) & 1u);
  return u >> 16;
}

// split v into bf16 hi + bf16(residual) lo; hi/lo are bf16 bit patterns.
__device__ __forceinline__ void bsplit(float v, unsigned int& h,
                                       unsigned int& l) {
  h = bf16r(v);
  float r = v - __uint_as_float(h << 16);
  l = bf16r(r);
}

__device__ __forceinline__ void acc_bf8(float4& lo, float4& hi, uint4 u) {
  lo.x += __uint_as_float(u.x << 16);
  lo.y += __uint_as_float(u.x & 0xffff0000u);
  lo.z += __uint_as_float(u.y << 16);
  lo.w += __uint_as_float(u.y & 0xffff0000u);
  hi.x += __uint_as_float(u.z << 16);
  hi.y += __uint_as_float(u.z & 0xffff0000u);
  hi.z += __uint_as_float(u.w << 16);
  hi.w += __uint_as_float(u.w & 0xffff0000u);
}

// ---- CSR build ----

__global__ __launch_bounds__(BLOCK) void binning_kernel(
    const int* __restrict__ src, const int* __restrict__ dst,
    int* __restrict__ bcursor, int* __restrict__ binned, int e, int npb) {
  __shared__ int h[NBUCKET];
  __shared__ int base[NBUCKET];
  for (int i = threadIdx.x; i < NBUCKET; i += BLOCK) h[i] = 0;
  __syncthreads();
  const int cbase = blockIdx.x * CHUNK;
#pragma unroll
  for (int k = 0; k < CHUNK; k += BLOCK * 4) {
    int i = cbase + k + threadIdx.x * 4;
    if (i + 3 < e) {
      int4 d4 = *(const int4*)(dst + i);
      atomicAdd(&h[d4.x / npb], 1);
      atomicAdd(&h[d4.y / npb], 1);
      atomicAdd(&h[d4.z / npb], 1);
      atomicAdd(&h[d4.w / npb], 1);
    } else {
      for (int t = 0; t < 4; ++t)
        if (i + t < e) atomicAdd(&h[dst[i + t] / npb], 1);
    }
  }
  __syncthreads();
  for (int i = threadIdx.x; i < NBUCKET; i += BLOCK) {
    int c = h[i];
    base[i] = c ? atomicAdd(&bcursor[i], c) : 0;
    h[i] = 0;
  }
  __syncthreads();
#pragma unroll
  for (int k = 0; k < CHUNK; k += BLOCK * 4) {
    int i = cbase + k + threadIdx.x * 4;
    if (i + 3 < e) {
      int4 d4 = *(const int4*)(dst + i);
      int4 s4 = *(const int4*)(src + i);
      int b0 = d4.x / npb, b1 = d4.y / npb, b2 = d4.z / npb, b3 = d4.w / npb;
      int o0 = atomicAdd(&h[b0], 1);
      int o1 = atomicAdd(&h[b1], 1);
      int o2 = atomicAdd(&h[b2], 1);
      int o3 = atomicAdd(&h[b3], 1);
      binned[b0 * SLOT + base[b0] + o0] = s4.x | ((d4.x - b0 * npb) << 17);
      binned[b1 * SLOT + base[b1] + o1] = s4.y | ((d4.y - b1 * npb) << 17);
      binned[b2 * SLOT + base[b2] + o2] = s4.z | ((d4.z - b2 * npb) << 17);
      binned[b3 * SLOT + base[b3] + o3] = s4.w | ((d4.w - b3 * npb) << 17);
    } else {
      for (int t = 0; t < 4; ++t) {
        if (i + t < e) {
          int d = dst[i + t];
          int bkt = d / npb;
          int lofs = atomicAdd(&h[bkt], 1);
          binned[bkt * SLOT + base[bkt] + lofs] =
              src[i + t] | ((d - bkt * npb) << 17);
        }
      }
    }
  }
}

// Per-node extents padded to 4-entry (16B) alignment; pad slots hold the
// dummy index n (zero row) so gathers can run whole int4 groups.
__global__ __launch_bounds__(BLOCK) void bucket_build(
    const int* __restrict__ binned, const int* __restrict__ bcursor,
    int* __restrict__ offs, int* __restrict__ cnt, float* __restrict__ dinv,
    int* __restrict__ csr_src, int n, int npb) {
  __shared__ int nhist[MAX_NPB];
  __shared__ int noff[MAX_NPB];
  __shared__ int lcsr[SLOT];
  __shared__ int ptot_sh;
  const int b = blockIdx.x;
  const int node_base = b * npb;
  const int nodes = min(npb, n - node_base);
  if (nodes <= 0) return;
  const int ebase = b * SLOT;
  const int ecnt = bcursor[b];
  for (int i = threadIdx.x; i < npb; i += BLOCK) nhist[i] = 0;
  __syncthreads();
  for (int i = threadIdx.x; i < ecnt; i += BLOCK)
    atomicAdd(&nhist[binned[ebase + i] >> 17], 1);
  __syncthreads();
  if (threadIdx.x < 64) {
    const int lane = threadIdx.x;
    const int bi = lane * 4;
    int v0 = (bi + 0 < nodes) ? nhist[bi + 0] : 0;
    int v1 = (bi + 1 < nodes) ? nhist[bi + 1] : 0;
    int v2 = (bi + 2 < nodes) ? nhist[bi + 2] : 0;
    int v3 = (bi + 3 < nodes) ? nhist[bi + 3] : 0;
    // pad each node's extent to a multiple of 4 entries
    int p0 = (v0 + 3) & ~3;
    int p1 = (v1 + 3) & ~3;
    int p2 = (v2 + 3) & ~3;
    int p3 = (v3 + 3) & ~3;
    int tsum = p0 + p1 + p2 + p3;
    int s = tsum;
#pragma unroll
    for (int o = 1; o < 64; o <<= 1) {
      int u = __shfl_up(s, o, 64);
      if (lane >= o) s += u;
    }
    int texcl = s - tsum;
    if (bi + 0 < nodes) noff[bi + 0] = texcl;
    if (bi + 1 < nodes) noff[bi + 1] = texcl + p0;
    if (bi + 2 < nodes) noff[bi + 2] = texcl + p0 + p1;
    if (bi + 3 < nodes) noff[bi + 3] = texcl + p0 + p1 + p2;
    if (lane == 63) ptot_sh = s;  // padded total
  }
  __syncthreads();
  const int ptot = min(ptot_sh, SLOT);
  for (int i = threadIdx.x; i < nodes; i += BLOCK) {
    int c = nhist[i];
    offs[node_base + i] = ebase + noff[i];
    cnt[node_base + i] = c;
    dinv[node_base + i] = rsqrtf((float)(c + 1));
  }
  for (int i = threadIdx.x; i < ptot; i += BLOCK) lcsr[i] = n;  // dummy fill
  __syncthreads();
  for (int i = threadIdx.x; i < ecnt; i += BLOCK) {
    int v = binned[ebase + i];
    int pos = atomicAdd(&noff[v >> 17], 1);
    lcsr[pos] = v & 0x1ffff;
  }
  __syncthreads();
  for (int i = threadIdx.x; i < ptot; i += BLOCK)
    csr_src[ebase + i] = lcsr[i];
}

// ---- weight prep: transpose to [n][k], split into bf16 hi/lo planes ----
// Wt ushort layout: [0,4096) W1t hi | [4096,8192) W1t lo |
//                   [8192,12288) W2t hi | [12288,16384) W2t lo |
//                   [16384,18432) W3t hi | [18432,20480) W3t lo
__global__ __launch_bounds__(BLOCK) void wprep_kernel(
    const float* __restrict__ W1, const float* __restrict__ W2,
    const float* __restrict__ W3, unsigned short* __restrict__ Wt) {
  int t = blockIdx.x * BLOCK + threadIdx.x;
  float v;
  int hi_off, lo_off;
  if (t < 4096) {
    int nn = t >> 6, k = t & 63;
    v = W1[k * 64 + nn];
    hi_off = t;
    lo_off = 4096 + t;
  } else if (t < 8192) {
    int i = t - 4096;
    int nn = i >> 6, k = i & 63;
    v = W2[k * 64 + nn];
    hi_off = 8192 + i;
    lo_off = 12288 + i;
  } else {
    int i = t - 8192;
    if (i >= 2048) return;
    int nn = i >> 6, k = i & 63;
    v = W3[k * 32 + nn];
    hi_off = 16384 + i;
    lo_off = 18432 + i;
  }
  unsigned int h, l;
  bsplit(v, h, l);
  Wt[hi_off] = (unsigned short)h;
  Wt[lo_off] = (unsigned short)l;
}

// ---- dense layers (MFMA) ----
// Frag layouts (mfma_f32_16x16x32_bf16, verified ladder m89/m92):
//   A: lane l holds A[l&15][8*(l>>4)+i], i=0..7 (one b128 from row-major)
//   B: lane l holds B[8*(l>>4)+i][l&15]  (one b128 from [n][k] storage)
//   C/D: col = l&15, row = (l>>4)*4 + reg
// Split-bf16: acc = Ahi*Bhi + Alo*Bhi + Ahi*Blo (3 MFMA per 16x16x32 tile).

// Layer-1: x (fp32) -> split-bf16 A-tile -> MFMA -> hbf = bf16(dinv * x@W1)
__global__ __launch_bounds__(BLOCK) void gemm1_kernel(
    const float* __restrict__ x, const unsigned short* __restrict__ Wt,
    const float* __restrict__ dinv, unsigned short* __restrict__ hbf, int n) {
  __shared__ unsigned short Ahi[16][72];  // 144B stride = 9x16B
  __shared__ unsigned short Alo[16][72];
  __shared__ float dvs[16];
  // zero the dummy row n (gather pad target for fused64)
  if (blockIdx.x == 0 && threadIdx.x < 8)
    *(uint4*)(hbf + (size_t)n * 64 + threadIdx.x * 8) =
        make_uint4(0u, 0u, 0u, 0u);
  const int r16 = threadIdx.x >> 4;
  const int c4 = (threadIdx.x & 15) * 4;
  const int node = blockIdx.x * 16 + r16;
  const int wv = threadIdx.x >> 6;         // ntile 0..3
  const int fr = threadIdx.x & 15;
  const int fq = (threadIdx.x >> 4) & 3;
  const unsigned short* wb = Wt + ((wv * 16 + fr) * 64) + fq * 8;
  bf16x8 bh0 = *(const bf16x8*)(wb);
  bf16x8 bh1 = *(const bf16x8*)(wb + 32);
  bf16x8 bl0 = *(const bf16x8*)(wb + 4096);
  bf16x8 bl1 = *(const bf16x8*)(wb + 4096 + 32);
  uint2 ph = make_uint2(0u, 0u), pl = make_uint2(0u, 0u);
  if (node < n) {
    f32x4 xv =
        __builtin_nontemporal_load((const f32x4*)(x + (size_t)node * 64 + c4));
    unsigned int h0, l0, h1, l1, h2, l2, h3, l3;
    bsplit(xv.x, h0, l0);
    bsplit(xv.y, h1, l1);
    bsplit(xv.z, h2, l2);
    bsplit(xv.w, h3, l3);
    ph = make_uint2(h0 | (h1 << 16), h2 | (h3 << 16));
    pl = make_uint2(l0 | (l1 << 16), l2 | (l3 << 16));
  }
  *(uint2*)(&Ahi[r16][c4]) = ph;
  *(uint2*)(&Alo[r16][c4]) = pl;
  if ((threadIdx.x & 15) == 0) dvs[r16] = (node < n) ? dinv[node] : 0.f;
  __syncthreads();
  bf16x8 ah0 = *(const bf16x8*)(&Ahi[fr][fq * 8]);
  bf16x8 ah1 = *(const bf16x8*)(&Ahi[fr][fq * 8 + 32]);
  bf16x8 aL0 = *(const bf16x8*)(&Alo[fr][fq * 8]);
  bf16x8 aL1 = *(const bf16x8*)(&Alo[fr][fq * 8 + 32]);
  f32x4 acc = {0.f, 0.f, 0.f, 0.f};
  acc = __builtin_amdgcn_mfma_f32_16x16x32_bf16(ah0, bh0, acc, 0, 0, 0);
  acc = __builtin_amdgcn_mfma_f32_16x16x32_bf16(aL0, bh0, acc, 0, 0, 0);
  acc = __builtin_amdgcn_mfma_f32_16x16x32_bf16(ah0, bl0, acc, 0, 0, 0);
  acc = __builtin_amdgcn_mfma_f32_16x16x32_bf16(ah1, bh1, acc, 0, 0, 0);
  acc = __builtin_amdgcn_mfma_f32_16x16x32_bf16(aL1, bh1, acc, 0, 0, 0);
  acc = __builtin_amdgcn_mfma_f32_16x16x32_bf16(ah1, bl1, acc, 0, 0, 0);
  const int col = wv * 16 + fr;
#pragma unroll
  for (int j = 0; j < 4; ++j) {
    int row = fq * 4 + j;
    int nd = blockIdx.x * 16 + row;
    if (nd < n)
      hbf[(size_t)nd * 64 + col] = (unsigned short)bf16r(dvs[row] * acc[j]);
  }
}

// Fused layer 1->2: agg (64, relu, b) -> MFMA gemm (64->64) -> bf16.
// Gather: 16 lanes/node = 8 col-lanes x 2 neighbor-halves; 16 nodes/block.
// 8 rows in flight per 16-lane group (2 int4 idx + 8 uint4 row loads).
__global__ __launch_bounds__(BLOCK) void fused_agg_gemm64(
    const unsigned short* __restrict__ hin, const int* __restrict__ csr_src,
    const int* __restrict__ offs, const int* __restrict__ cnt,
    const float* __restrict__ dinv, const float* __restrict__ bias,
    const unsigned short* __restrict__ Wt, unsigned short* __restrict__ hout,
    int n) {
  __shared__ unsigned short Ahi[16][72];
  __shared__ unsigned short Alo[16][72];
  __shared__ float dvs[16];
  if (blockIdx.x == 0 && threadIdx.x < 8)  // zero dummy row for fused32
    *(uint4*)(hout + (size_t)n * 64 + threadIdx.x * 8) =
        make_uint4(0u, 0u, 0u, 0u);
  const int g = threadIdx.x >> 4;
  const int lane16 = threadIdx.x & 15;
  const int colgrp = lane16 & 7;
  const int half = lane16 >> 3;
  const int c8 = colgrp * 8;
  const int node = blockIdx.x * 16 + g;
  const bool valid = node < n;
  float dnode = 0.f;
  uint4 qh = make_uint4(0u, 0u, 0u, 0u), ql = make_uint4(0u, 0u, 0u, 0u);
  const char* hbase = (const char*)hin + c8 * 2;  // lane's 16B column slice
  if (valid) {
    const int start = offs[node];  // 4-aligned
    const int cn = cnt[node];
    const int* cp = csr_src + start;
    float4 l0 = make_float4(0.f, 0.f, 0.f, 0.f), h0 = l0;
    float4 l1 = l0, h1 = l0, l2 = l0, h2 = l0, l3 = l0, h3 = l0;
    if (half == 0)
      acc_bf8(l0, h0, *(const uint4*)(hbase + ((unsigned)node << 7)));  // self
    int j = half * 4;
    for (; j + 8 < cn; j += 16) {  // two 4-groups of this half in flight
      int4 sv0 = *(const int4*)(cp + j);
      int4 sv1 = *(const int4*)(cp + j + 8);
      uint4 u0 = *(const uint4*)(hbase + ((unsigned)sv0.x << 7));
      uint4 u1 = *(const uint4*)(hbase + ((unsigned)sv0.y << 7));
      uint4 u2 = *(const uint4*)(hbase + ((unsigned)sv0.z << 7));
      uint4 u3 = *(const uint4*)(hbase + ((unsigned)sv0.w << 7));
      uint4 u4 = *(const uint4*)(hbase + ((unsigned)sv1.x << 7));
      uint4 u5 = *(const uint4*)(hbase + ((unsigned)sv1.y << 7));
      uint4 u6 = *(const uint4*)(hbase + ((unsigned)sv1.z << 7));
      uint4 u7 = *(const uint4*)(hbase + ((unsigned)sv1.w << 7));
      acc_bf8(l0, h0, u0);
      acc_bf8(l1, h1, u1);
      acc_bf8(l2, h2, u2);
      acc_bf8(l3, h3, u3);
      acc_bf8(l0, h0, u4);
      acc_bf8(l1, h1, u5);
      acc_bf8(l2, h2, u6);
      acc_bf8(l3, h3, u7);
    }
    if (j < cn) {  // last 4-group of this half
      int4 sv = *(const int4*)(cp + j);
      uint4 u0 = *(const uint4*)(hbase + ((unsigned)sv.x << 7));
      uint4 u1 = *(const uint4*)(hbase + ((unsigned)sv.y << 7));
      uint4 u2 = *(const uint4*)(hbase + ((unsigned)sv.z << 7));
      uint4 u3 = *(const uint4*)(hbase + ((unsigned)sv.w << 7));
      acc_bf8(l0, h0, u0);
      acc_bf8(l1, h1, u1);
      acc_bf8(l2, h2, u2);
      acc_bf8(l3, h3, u3);
    }
    float4 alo = make_float4((l0.x + l1.x) + (l2.x + l3.x),
                             (l0.y + l1.y) + (l2.y + l3.y),
                             (l0.z + l1.z) + (l2.z + l3.z),
                             (l0.w + l1.w) + (l2.w + l3.w));
    float4 ahi = make_float4((h0.x + h1.x) + (h2.x + h3.x),
                             (h0.y + h1.y) + (h2.y + h3.y),
                             (h0.z + h1.z) + (h2.z + h3.z),
                             (h0.w + h1.w) + (h2.w + h3.w));
    alo.x += __shfl_xor(alo.x, 8); alo.y += __shfl_xor(alo.y, 8);
    alo.z += __shfl_xor(alo.z, 8); alo.w += __shfl_xor(alo.w, 8);
    ahi.x += __shfl_xor(ahi.x, 8); ahi.y += __shfl_xor(ahi.y, 8);
    ahi.z += __shfl_xor(ahi.z, 8); ahi.w += __shfl_xor(ahi.w, 8);
    dnode = dinv[node];
    if (half == 0) {
      float4 b4l = *(const float4*)(bias + c8);
      float4 b4h = *(const float4*)(bias + c8 + 4);
      float v0 = fmaxf(fmaf(dnode, alo.x, b4l.x), 0.f);
      float v1 = fmaxf(fmaf(dnode, alo.y, b4l.y), 0.f);
      float v2 = fmaxf(fmaf(dnode, alo.z, b4l.z), 0.f);
      float v3 = fmaxf(fmaf(dnode, alo.w, b4l.w), 0.f);
      float v4 = fmaxf(fmaf(dnode, ahi.x, b4h.x), 0.f);
      float v5 = fmaxf(fmaf(dnode, ahi.y, b4h.y), 0.f);
      float v6 = fmaxf(fmaf(dnode, ahi.z, b4h.z), 0.f);
      float v7 = fmaxf(fmaf(dnode, ahi.w, b4h.w), 0.f);
      unsigned int h0u, l0u, h1u, l1u, h2u, l2u, h3u, l3u;
      unsigned int h4u, l4u, h5u, l5u, h6u, l6u, h7u, l7u;
      bsplit(v0, h0u, l0u); bsplit(v1, h1u, l1u);
      bsplit(v2, h2u, l2u); bsplit(v3, h3u, l3u);
      bsplit(v4, h4u, l4u); bsplit(v5, h5u, l5u);
      bsplit(v6, h6u, l6u); bsplit(v7, h7u, l7u);
      qh = make_uint4(h0u | (h1u << 16), h2u | (h3u << 16),
                      h4u | (h5u << 16), h6u | (h7u << 16));
      ql = make_uint4(l0u | (l1u << 16), l2u | (l3u << 16),
                      l4u | (l5u << 16), l6u | (l7u << 16));
    }
  }
  if (half == 0) {
    *(uint4*)(&Ahi[g][c8]) = qh;
    *(uint4*)(&Alo[g][c8]) = ql;
    if (lane16 == 0) dvs[g] = dnode;
  }
  // B frags: issue before barrier so latency overlaps the sync.
  const int wv = threadIdx.x >> 6;
  const int fr = threadIdx.x & 15;
  const int fq = (threadIdx.x >> 4) & 3;
  const unsigned short* wb = Wt + ((wv * 16 + fr) * 64) + fq * 8;
  bf16x8 bh0 = *(const bf16x8*)(wb);
  bf16x8 bh1 = *(const bf16x8*)(wb + 32);
  bf16x8 bl0 = *(const bf16x8*)(wb + 4096);
  bf16x8 bl1 = *(const bf16x8*)(wb + 4096 + 32);
  __syncthreads();
  bf16x8 ah0 = *(const bf16x8*)(&Ahi[fr][fq * 8]);
  bf16x8 ah1 = *(const bf16x8*)(&Ahi[fr][fq * 8 + 32]);
  bf16x8 aL0 = *(const bf16x8*)(&Alo[fr][fq * 8]);
  bf16x8 aL1 = *(const bf16x8*)(&Alo[fr][fq * 8 + 32]);
  f32x4 acc = {0.f, 0.f, 0.f, 0.f};
  acc = __builtin_amdgcn_mfma_f32_16x16x32_bf16(ah0, bh0, acc, 0, 0, 0);
  acc = __builtin_amdgcn_mfma_f32_16x16x32_bf16(aL0, bh0, acc, 0, 0, 0);
  acc = __builtin_amdgcn_mfma_f32_16x16x32_bf16(ah0, bl0, acc, 0, 0, 0);
  acc = __builtin_amdgcn_mfma_f32_16x16x32_bf16(ah1, bh1, acc, 0, 0, 0);
  acc = __builtin_amdgcn_mfma_f32_16x16x32_bf16(aL1, bh1, acc, 0, 0, 0);
  acc = __builtin_amdgcn_mfma_f32_16x16x32_bf16(ah1, bl1, acc, 0, 0, 0);
  const int col = wv * 16 + fr;
#pragma unroll
  for (int j = 0; j < 4; ++j) {
    int row = fq * 4 + j;
    int nd = blockIdx.x * 16 + row;
    if (nd < n)
      hout[(size_t)nd * 64 + col] = (unsigned short)bf16r(dvs[row] * acc[j]);
  }
}

// Fused layer 2->3: agg (64, relu, b) -> MFMA gemm (64->32) -> bf16.
// Gather: 8 lanes/node, 32 nodes/block, 8 rows in flight.
__global__ __launch_bounds__(BLOCK) void fused_agg_gemm32(
    const unsigned short* __restrict__ hin, const int* __restrict__ csr_src,
    const int* __restrict__ offs, const int* __restrict__ cnt,
    const float* __restrict__ dinv, const float* __restrict__ bias,
    const unsigned short* __restrict__ Wt, unsigned short* __restrict__ hout,
    int n) {
  __shared__ unsigned short Ahi[32][72];
  __shared__ unsigned short Alo[32][72];
  __shared__ float dvs[32];
  if (blockIdx.x == 0 && threadIdx.x < 4)  // zero dummy 32-wide row for agg3
    *(uint4*)(hout + (size_t)n * 32 + threadIdx.x * 8) =
        make_uint4(0u, 0u, 0u, 0u);
  const int g = threadIdx.x >> 3;
  const int lane8 = threadIdx.x & 7;
  const int c8 = lane8 * 8;
  const int node = blockIdx.x * 32 + g;
  const bool valid = node < n;
  float dnode = 0.f;
  uint4 qh = make_uint4(0u, 0u, 0u, 0u), ql = make_uint4(0u, 0u, 0u, 0u);
  const char* hbase = (const char*)hin + c8 * 2;
  if (valid) {
    const int start = offs[node];  // 4-aligned
    const int cn = cnt[node];
    const int* cp = csr_src + start;
    float4 l0 = make_float4(0.f, 0.f, 0.f, 0.f), h0 = l0;
    float4 l1 = l0, h1 = l0, l2 = l0, h2 = l0, l3 = l0, h3 = l0;
    acc_bf8(l0, h0, *(const uint4*)(hbase + ((unsigned)node << 7)));
    int j = 0;
    for (; j + 4 < cn; j += 8) {  // two 4-groups in flight
      int4 sv0 = *(const int4*)(cp + j);
      int4 sv1 = *(const int4*)(cp + j + 4);
      uint4 u0 = *(const uint4*)(hbase + ((unsigned)sv0.x << 7));
      uint4 u1 = *(const uint4*)(hbase + ((unsigned)sv0.y << 7));
      uint4 u2 = *(const uint4*)(hbase + ((unsigned)sv0.z << 7));
      uint4 u3 = *(const uint4*)(hbase + ((unsigned)sv0.w << 7));
      uint4 u4 = *(const uint4*)(hbase + ((unsigned)sv1.x << 7));
      uint4 u5 = *(const uint4*)(hbase + ((unsigned)sv1.y << 7));
      uint4 u6 = *(const uint4*)(hbase + ((unsigned)sv1.z << 7));
      uint4 u7 = *(const uint4*)(hbase + ((unsigned)sv1.w << 7));
      acc_bf8(l0, h0, u0);
      acc_bf8(l1, h1, u1);
      acc_bf8(l2, h2, u2);
      acc_bf8(l3, h3, u3);
      acc_bf8(l0, h0, u4);
      acc_bf8(l1, h1, u5);
      acc_bf8(l2, h2, u6);
      acc_bf8(l3, h3, u7);
    }
    if (j < cn) {
      int4 sv = *(const int4*)(cp + j);
      uint4 u0 = *(const uint4*)(hbase + ((unsigned)sv.x << 7));
      uint4 u1 = *(const uint4*)(hbase + ((unsigned)sv.y << 7));
      uint4 u2 = *(const uint4*)(hbase + ((unsigned)sv.z << 7));
      uint4 u3 = *(const uint4*)(hbase + ((unsigned)sv.w << 7));
      acc_bf8(l0, h0, u0);
      acc_bf8(l1, h1, u1);
      acc_bf8(l2, h2, u2);
      acc_bf8(l3, h3, u3);
    }
    float4 alo = make_float4((l0.x + l1.x) + (l2.x + l3.x),
                             (l0.y + l1.y) + (l2.y + l3.y),
                             (l0.z + l1.z) + (l2.z + l3.z),
                             (l0.w + l1.w) + (l2.w + l3.w));
    float4 ahi = make_float4((h0.x + h1.x) + (h2.x + h3.x),
                             (h0.y + h1.y) + (h2.y + h3.y),
                             (h0.z + h1.z) + (h2.z + h3.z),
                             (h0.w + h1.w) + (h2.w + h3.w));
    dnode = dinv[node];
    float4 b4l = *(const float4*)(bias + c8);
    float4 b4h = *(const float4*)(bias + c8 + 4);
    float v0 = fmaxf(fmaf(dnode, alo.x, b4l.x), 0.f);
    float v1 = fmaxf(fmaf(dnode, alo.y, b4l.y), 0.f);
    float v2 = fmaxf(fmaf(dnode, alo.z, b4l.z), 0.f);
    float v3 = fmaxf(fmaf(dnode, alo.w, b4l.w), 0.f);
    float v4 = fmaxf(fmaf(dnode, ahi.x, b4h.x), 0.f);
    float v5 = fmaxf(fmaf(dnode, ahi.y, b4h.y), 0.f);
    float v6 = fmaxf(fmaf(dnode, ahi.z, b4h.z), 0.f);
    float v7 = fmaxf(fmaf(dnode, ahi.w, b4h.w), 0.f);
    unsigned int h0u, l0u, h1u, l1u, h2u, l2u, h3u, l3u;
    unsigned int h4u, l4u, h5u, l5u, h6u, l6u, h7u, l7u;
    bsplit(v0, h0u, l0u); bsplit(v1, h1u, l1u);
    bsplit(v2, h2u, l2u); bsplit(v3, h3u, l3u);
    bsplit(v4, h4u, l4u); bsplit(v5, h5u, l5u);
    bsplit(v6, h6u, l6u); bsplit(v7, h7u, l7u);
    qh = make_uint4(h0u | (h1u << 16), h2u | (h3u << 16),
                    h4u | (h5u << 16), h6u | (h7u << 16));
    ql = make_uint4(l0u | (l1u << 16), l2u | (l3u << 16),
                    l4u | (l5u << 16), l6u | (l7u << 16));
  }
  *(uint4*)(&Ahi[g][c8]) = qh;
  *(uint4*)(&Alo[g][c8]) = ql;
  if (lane8 == 0) dvs[g] = dnode;
  const int wv = threadIdx.x >> 6;
  const int mt = wv >> 1;   // m-tile 0..1
  const int nt = wv & 1;    // n-tile 0..1
  const int fr = threadIdx.x & 15;
  const int fq = (threadIdx.x >> 4) & 3;
  const unsigned short* wb = Wt + ((nt * 16 + fr) * 64) + fq * 8;
  bf16x8 bh0 = *(const bf16x8*)(wb);
  bf16x8 bh1 = *(const bf16x8*)(wb + 32);
  bf16x8 bl0 = *(const bf16x8*)(wb + 2048);
  bf16x8 bl1 = *(const bf16x8*)(wb + 2048 + 32);
  __syncthreads();
  bf16x8 ah0 = *(const bf16x8*)(&Ahi[mt * 16 + fr][fq * 8]);
  bf16x8 ah1 = *(const bf16x8*)(&Ahi[mt * 16 + fr][fq * 8 + 32]);
  bf16x8 aL0 = *(const bf16x8*)(&Alo[mt * 16 + fr][fq * 8]);
  bf16x8 aL1 = *(const bf16x8*)(&Alo[mt * 16 + fr][fq * 8 + 32]);
  f32x4 acc = {0.f, 0.f, 0.f, 0.f};
  acc = __builtin_amdgcn_mfma_f32_16x16x32_bf16(ah0, bh0, acc, 0, 0, 0);
  acc = __builtin_amdgcn_mfma_f32_16x16x32_bf16(aL0, bh0, acc, 0, 0, 0);
  acc = __builtin_amdgcn_mfma_f32_16x16x32_bf16(ah0, bl0, acc, 0, 0, 0);
  acc = __builtin_amdgcn_mfma_f32_16x16x32_bf16(ah1, bh1, acc, 0, 0, 0);
  acc = __builtin_amdgcn_mfma_f32_16x16x32_bf16(aL1, bh1, acc, 0, 0, 0);
  acc = __builtin_amdgcn_mfma_f32_16x16x32_bf16(ah1, bl1, acc, 0, 0, 0);
  const int col = nt * 16 + fr;
#pragma unroll
  for (int j = 0; j < 4; ++j) {
    int row = mt * 16 + fq * 4 + j;
    int nd = blockIdx.x * 32 + row;
    if (nd < n)
      hout[(size_t)nd * 32 + col] = (unsigned short)bf16r(dvs[row] * acc[j]);
  }
}

// Final aggregation (F=32, no relu): 4 lanes/node, 64 nodes/block.
__global__ __launch_bounds__(BLOCK) void agg3_kernel(
    const unsigned short* __restrict__ hbf, const int* __restrict__ csr_src,
    const int* __restrict__ offs, const int* __restrict__ cnt,
    const float* __restrict__ dinv, const float* __restrict__ bias,
    float* __restrict__ out, int n) {
  constexpr int F = 32;
  const int node = blockIdx.x * 64 + (int)(threadIdx.x >> 2);
  const int c8 = (threadIdx.x & 3) * 8;
  if (node >= n) return;
  const int start = offs[node];  // 4-aligned
  const int cn = cnt[node];
  const int* cp = csr_src + start;
  const char* hbase = (const char*)hbf + c8 * 2;
  float4 l0 = make_float4(0.f, 0.f, 0.f, 0.f), h0 = l0;
  float4 l1 = l0, h1 = l0, l2 = l0, h2 = l0, l3 = l0, h3 = l0;
  acc_bf8(l0, h0, *(const uint4*)(hbase + ((unsigned)node << 6)));
  for (int j = 0; j < cn; j += 4) {
    int4 sv = *(const int4*)(cp + j);
    uint4 u0 = *(const uint4*)(hbase + ((unsigned)sv.x << 6));
    uint4 u1 = *(const uint4*)(hbase + ((unsigned)sv.y << 6));
    uint4 u2 = *(const uint4*)(hbase + ((unsigned)sv.z << 6));
    uint4 u3 = *(const uint4*)(hbase + ((unsigned)sv.w << 6));
    acc_bf8(l0, h0, u0);
    acc_bf8(l1, h1, u1);
    acc_bf8(l2, h2, u2);
    acc_bf8(l3, h3, u3);
  }
  float4 alo = make_float4((l0.x + l1.x) + (l2.x + l3.x),
                           (l0.y + l1.y) + (l2.y + l3.y),
                           (l0.z + l1.z) + (l2.z + l3.z),
                           (l0.w + l1.w) + (l2.w + l3.w));
  float4 ahi = make_float4((h0.x + h1.x) + (h2.x + h3.x),
                           (h0.y + h1.y) + (h2.y + h3.y),
                           (h0.z + h1.z) + (h2.z + h3.z),
                           (h0.w + h1.w) + (h2.w + h3.w));
  float d = dinv[node];
  float4 blo = *(const float4*)(bias + c8);
  float4 bhi = *(const float4*)(bias + c8 + 4);
  f32x4 vlo = {fmaf(d, alo.x, blo.x), fmaf(d, alo.y, blo.y),
               fmaf(d, alo.z, blo.z), fmaf(d, alo.w, blo.w)};
  f32x4 vhi = {fmaf(d, ahi.x, bhi.x), fmaf(d, ahi.y, bhi.y),
               fmaf(d, ahi.z, bhi.z), fmaf(d, ahi.w, bhi.w)};
  float* op = out + (size_t)node * F + c8;
  __builtin_nontemporal_store(vlo, (f32x4*)op);
  __builtin_nontemporal_store(vhi, (f32x4*)(op + 4));
}

static inline size_t align_up(size_t v, size_t a) { return (v + a - 1) & ~(a - 1); }

extern "C" void kernel_launch(void* const* d_in, const int* in_sizes, int n_in,
                              void* d_out, int out_size, void* d_ws, size_t ws_size,
                              hipStream_t stream) {
  const float* x = (const float*)d_in[0];
  const int* edge_index = (const int*)d_in[1];
  const float* W1 = (const float*)d_in[2];
  const float* b1 = (const float*)d_in[3];
  const float* W2 = (const float*)d_in[4];
  const float* b2 = (const float*)d_in[5];
  const float* W3 = (const float*)d_in[6];
  const float* b3 = (const float*)d_in[7];
  float* out = (float*)d_out;

  const int n = in_sizes[0] / 64;       // 100000
  const int e = in_sizes[1] / 2;        // 1600000
  const int* e_src = edge_index;
  const int* e_dst = edge_index + e;
  const int npb = (n + NBUCKET - 1) / NBUCKET;  // 196

  char* ws = (char*)d_ws;
  size_t off = 0;
  int* bcursor = (int*)(ws + off); off = align_up(off + NBUCKET * 4, 512);
  int* offs    = (int*)(ws + off); off = align_up(off + (size_t)n * 4, 512);
  int* cnt     = (int*)(ws + off); off = align_up(off + (size_t)n * 4, 512);
  float* dinv  = (float*)(ws + off); off = align_up(off + (size_t)n * 4, 512);
  int* binned  = (int*)(ws + off); off = align_up(off + (size_t)NBUCKET * SLOT * 4, 512);
  int* csr_src = (int*)(ws + off); off = align_up(off + (size_t)NBUCKET * SLOT * 4, 512);
  unsigned short* hbuf_a = (unsigned short*)(ws + off);
  off = align_up(off + (size_t)(n + 1) * 64 * 2, 512);  // +1 dummy row
  unsigned short* hbuf_b = (unsigned short*)(ws + off);
  off = align_up(off + (size_t)(n + 1) * 64 * 2, 512);  // +1 dummy row
  unsigned short* Wt = (unsigned short*)(ws + off);
  off = align_up(off + (size_t)20480 * 2, 512);
  (void)ws_size;

  unsigned short* Wt1 = Wt;            // 64x64 hi/lo
  unsigned short* Wt2 = Wt + 8192;     // 64x64 hi/lo
  unsigned short* Wt3 = Wt + 16384;    // 32x64 hi/lo

  const int gC = (e + CHUNK - 1) / CHUNK;

  hipMemsetAsync(bcursor, 0, NBUCKET * 4, stream);
  wprep_kernel<<<40, BLOCK, 0, stream>>>(W1, W2, W3, Wt);
  binning_kernel<<<gC, BLOCK, 0, stream>>>(e_src, e_dst, bcursor, binned, e, npb);
  bucket_build<<<NBUCKET, BLOCK, 0, stream>>>(binned, bcursor, offs, cnt, dinv,
                                              csr_src, n, npb);

  gemm1_kernel<<<(n + 15) / 16, BLOCK, 0, stream>>>(x, Wt1, dinv, hbuf_a, n);
  fused_agg_gemm64<<<(n + 15) / 16, BLOCK, 0, stream>>>(
      hbuf_a, csr_src, offs, cnt, dinv, b1, Wt2, hbuf_b, n);
  fused_agg_gemm32<<<(n + 31) / 32, BLOCK, 0, stream>>>(
      hbuf_b, csr_src, offs, cnt, dinv, b2, Wt3, hbuf_a, n);
  agg3_kernel<<<(n + 63) / 64, BLOCK, 0, stream>>>(hbuf_a, csr_src, offs, cnt,
                                                   dinv, b3, out, n);
}

// Round 5
// 236.034 us; speedup vs baseline: 1.0052x; 1.0052x over previous
//
#include <hip/hip_runtime.h>
#include <hip/hip_bf16.h>

// GCN 3-layer forward on MI355X.  (R15: consolidation — wprep fold, direct
// CSR scatter, agg3 8-deep)
// h' = bf16( dinv .* (x @ W) );  out = relu(dinv .* (h'[i]+sum h'[src]) + b)
//
// ROOFLINE NOTE (R11-R14 evidence): the gather kernels are pinned at
// 2.0-2.3 TB/s L2-miss BW in every configuration (occupancy 33-50%,
// 4/8-deep MLP, persistent/per-tile grids).  FETCH ~83MB/dispatch equals
// the compulsory per-XCD stream (12.8MB hbuf x 8 XCD x 81% row coverage);
// capacity misses ~0.  2.1TB/s / 8 XCD / 2.4GHz ~ one 128B line/cy/XCD =
// the XCD<->fabric port rate.  Gather floor ~(83+83+41)MB / 2.3TB/s ~90us.
// This round only trims non-gather slack: CSR build, dispatch count, agg3
// unroll.
//
// CSR via single-pass bucket binning (arena slots); neighbor lists padded
// to 4-entry alignment with DUMMY index n (zeroed row in each h-buffer) ->
// gather loops are pure int4 groups.  Gathers: fused64 16 lanes/node
// (measured optimum), fused32 8, agg3 4; all 8 rows in flight.
// Dense gemms on mfma_f32_16x16x32_bf16, split-bf16 (hi + residual lo)
// on both operands (~fp32 product precision).

#define BLOCK 256
#define NBUCKET 512
#define CHUNK 4096
#define SLOT 4608
#define MAX_NPB 256

typedef float f32x4 __attribute__((ext_vector_type(4)));
typedef short bf16x8 __attribute__((ext_vector_type(8)));

__device__ __forceinline__ unsigned int bf16r(float f) {
  unsigned int u = __float_as_uint(f);
  u += 0x7fffu + ((u >> 16) & 1u);
  return u >> 16;
}

// split v into bf16 hi + bf16(residual) lo; hi/lo are bf16 bit patterns.
__device__ __forceinline__ void bsplit(float v, unsigned int& h,
                                       unsigned int& l) {
  h = bf16r(v);
  float r = v - __uint_as_float(h << 16);
  l = bf16r(r);
}

__device__ __forceinline__ void acc_bf8(float4& lo, float4& hi, uint4 u) {
  lo.x += __uint_as_float(u.x << 16);
  lo.y += __uint_as_float(u.x & 0xffff0000u);
  lo.z += __uint_as_float(u.y << 16);
  lo.w += __uint_as_float(u.y & 0xffff0000u);
  hi.x += __uint_as_float(u.z << 16);
  hi.y += __uint_as_float(u.z & 0xffff0000u);
  hi.z += __uint_as_float(u.w << 16);
  hi.w += __uint_as_float(u.w & 0xffff0000u);
}

// ---- CSR build (binning also performs weight prep in blocks 0-79) ----
// Wt ushort layout: [0,4096) W1t hi | [4096,8192) W1t lo |
//                   [8192,12288) W2t hi | [12288,16384) W2t lo |
//                   [16384,18432) W3t hi | [18432,20480) W3t lo

__global__ __launch_bounds__(BLOCK) void binning_kernel(
    const int* __restrict__ src, const int* __restrict__ dst,
    int* __restrict__ bcursor, int* __restrict__ binned,
    const float* __restrict__ W1, const float* __restrict__ W2,
    const float* __restrict__ W3, unsigned short* __restrict__ Wt, int e,
    int npb) {
  // weight prep fold: one element per thread in blocks 0-79
  {
    int t = blockIdx.x * BLOCK + threadIdx.x;
    if (t < 20480) {
      float v;
      int hi_off, lo_off;
      if (t < 4096) {
        int nn = t >> 6, k = t & 63;
        v = W1[k * 64 + nn];
        hi_off = t;
        lo_off = 4096 + t;
      } else if (t < 8192) {
        int i = t - 4096;
        int nn = i >> 6, k = i & 63;
        v = W2[k * 64 + nn];
        hi_off = 8192 + i;
        lo_off = 12288 + i;
      } else {
        int i = t - 8192;
        if (i < 2048) {
          int nn = i >> 6, k = i & 63;
          v = W3[k * 32 + nn];
          hi_off = 16384 + i;
          lo_off = 18432 + i;
        } else {
          hi_off = -1;
          lo_off = -1;
          v = 0.f;
        }
      }
      if (hi_off >= 0) {
        unsigned int h, l;
        bsplit(v, h, l);
        Wt[hi_off] = (unsigned short)h;
        Wt[lo_off] = (unsigned short)l;
      }
    }
  }
  __shared__ int h[NBUCKET];
  __shared__ int base[NBUCKET];
  for (int i = threadIdx.x; i < NBUCKET; i += BLOCK) h[i] = 0;
  __syncthreads();
  const int cbase = blockIdx.x * CHUNK;
#pragma unroll
  for (int k = 0; k < CHUNK; k += BLOCK * 4) {
    int i = cbase + k + threadIdx.x * 4;
    if (i + 3 < e) {
      int4 d4 = *(const int4*)(dst + i);
      atomicAdd(&h[d4.x / npb], 1);
      atomicAdd(&h[d4.y / npb], 1);
      atomicAdd(&h[d4.z / npb], 1);
      atomicAdd(&h[d4.w / npb], 1);
    } else {
      for (int t = 0; t < 4; ++t)
        if (i + t < e) atomicAdd(&h[dst[i + t] / npb], 1);
    }
  }
  __syncthreads();
  for (int i = threadIdx.x; i < NBUCKET; i += BLOCK) {
    int c = h[i];
    base[i] = c ? atomicAdd(&bcursor[i], c) : 0;
    h[i] = 0;
  }
  __syncthreads();
#pragma unroll
  for (int k = 0; k < CHUNK; k += BLOCK * 4) {
    int i = cbase + k + threadIdx.x * 4;
    if (i + 3 < e) {
      int4 d4 = *(const int4*)(dst + i);
      int4 s4 = *(const int4*)(src + i);
      int b0 = d4.x / npb, b1 = d4.y / npb, b2 = d4.z / npb, b3 = d4.w / npb;
      int o0 = atomicAdd(&h[b0], 1);
      int o1 = atomicAdd(&h[b1], 1);
      int o2 = atomicAdd(&h[b2], 1);
      int o3 = atomicAdd(&h[b3], 1);
      binned[b0 * SLOT + base[b0] + o0] = s4.x | ((d4.x - b0 * npb) << 17);
      binned[b1 * SLOT + base[b1] + o1] = s4.y | ((d4.y - b1 * npb) << 17);
      binned[b2 * SLOT + base[b2] + o2] = s4.z | ((d4.z - b2 * npb) << 17);
      binned[b3 * SLOT + base[b3] + o3] = s4.w | ((d4.w - b3 * npb) << 17);
    } else {
      for (int t = 0; t < 4; ++t) {
        if (i + t < e) {
          int d = dst[i + t];
          int bkt = d / npb;
          int lofs = atomicAdd(&h[bkt], 1);
          binned[bkt * SLOT + base[bkt] + lofs] =
              src[i + t] | ((d - bkt * npb) << 17);
        }
      }
    }
  }
}

// Per-node extents padded to 4-entry (16B) alignment; pad slots hold the
// dummy index n (zero row).  Direct global scatter (csr_src region is
// L2-resident); pad-fill runs in the same phase (disjoint addresses).
__global__ __launch_bounds__(BLOCK) void bucket_build(
    const int* __restrict__ binned, const int* __restrict__ bcursor,
    int* __restrict__ offs, int* __restrict__ cnt, float* __restrict__ dinv,
    int* __restrict__ csr_src, int n, int npb) {
  __shared__ int nhist[MAX_NPB];
  __shared__ int nbase[MAX_NPB];
  __shared__ int noff[MAX_NPB];
  const int b = blockIdx.x;
  const int node_base = b * npb;
  const int nodes = min(npb, n - node_base);
  if (nodes <= 0) return;
  const int ebase = b * SLOT;
  const int ecnt = bcursor[b];
  for (int i = threadIdx.x; i < npb; i += BLOCK) nhist[i] = 0;
  __syncthreads();
  for (int i = threadIdx.x; i < ecnt; i += BLOCK)
    atomicAdd(&nhist[binned[ebase + i] >> 17], 1);
  __syncthreads();
  if (threadIdx.x < 64) {
    const int lane = threadIdx.x;
    const int bi = lane * 4;
    int v0 = (bi + 0 < nodes) ? nhist[bi + 0] : 0;
    int v1 = (bi + 1 < nodes) ? nhist[bi + 1] : 0;
    int v2 = (bi + 2 < nodes) ? nhist[bi + 2] : 0;
    int v3 = (bi + 3 < nodes) ? nhist[bi + 3] : 0;
    // pad each node's extent to a multiple of 4 entries
    int p0 = (v0 + 3) & ~3;
    int p1 = (v1 + 3) & ~3;
    int p2 = (v2 + 3) & ~3;
    int p3 = (v3 + 3) & ~3;
    int tsum = p0 + p1 + p2 + p3;
    int s = tsum;
#pragma unroll
    for (int o = 1; o < 64; o <<= 1) {
      int u = __shfl_up(s, o, 64);
      if (lane >= o) s += u;
    }
    int texcl = s - tsum;
    if (bi + 0 < nodes) { nbase[bi + 0] = texcl; noff[bi + 0] = texcl; }
    if (bi + 1 < nodes) {
      nbase[bi + 1] = texcl + p0;
      noff[bi + 1] = texcl + p0;
    }
    if (bi + 2 < nodes) {
      nbase[bi + 2] = texcl + p0 + p1;
      noff[bi + 2] = texcl + p0 + p1;
    }
    if (bi + 3 < nodes) {
      nbase[bi + 3] = texcl + p0 + p1 + p2;
      noff[bi + 3] = texcl + p0 + p1 + p2;
    }
  }
  __syncthreads();
  for (int i = threadIdx.x; i < nodes; i += BLOCK) {
    int c = nhist[i];
    offs[node_base + i] = ebase + nbase[i];
    cnt[node_base + i] = c;
    dinv[node_base + i] = rsqrtf((float)(c + 1));
  }
  // scatter real entries (addresses [nbase, nbase+c) per node)
  for (int i = threadIdx.x; i < ecnt; i += BLOCK) {
    int v = binned[ebase + i];
    int pos = atomicAdd(&noff[v >> 17], 1);
    csr_src[ebase + pos] = v & 0x1ffff;
  }
  // pad fill (disjoint addresses [nbase+c, nbase+pad4(c)) per node)
  for (int i = threadIdx.x; i < nodes; i += BLOCK) {
    int c = nhist[i];
    int basei = ebase + nbase[i] + c;
    int pads = ((c + 3) & ~3) - c;
    for (int k = 0; k < pads; ++k) csr_src[basei + k] = n;
  }
}

// ---- dense layers (MFMA) ----
// Frag layouts (mfma_f32_16x16x32_bf16, verified ladder m89/m92):
//   A: lane l holds A[l&15][8*(l>>4)+i], i=0..7 (one b128 from row-major)
//   B: lane l holds B[8*(l>>4)+i][l&15]  (one b128 from [n][k] storage)
//   C/D: col = l&15, row = (l>>4)*4 + reg
// Split-bf16: acc = Ahi*Bhi + Alo*Bhi + Ahi*Blo (3 MFMA per 16x16x32 tile).

// Layer-1: x (fp32) -> split-bf16 A-tile -> MFMA -> hbf = bf16(dinv * x@W1)
__global__ __launch_bounds__(BLOCK) void gemm1_kernel(
    const float* __restrict__ x, const unsigned short* __restrict__ Wt,
    const float* __restrict__ dinv, unsigned short* __restrict__ hbf, int n) {
  __shared__ unsigned short Ahi[16][72];  // 144B stride = 9x16B
  __shared__ unsigned short Alo[16][72];
  __shared__ float dvs[16];
  // zero the dummy row n (gather pad target for fused64)
  if (blockIdx.x == 0 && threadIdx.x < 8)
    *(uint4*)(hbf + (size_t)n * 64 + threadIdx.x * 8) =
        make_uint4(0u, 0u, 0u, 0u);
  const int r16 = threadIdx.x >> 4;
  const int c4 = (threadIdx.x & 15) * 4;
  const int node = blockIdx.x * 16 + r16;
  const int wv = threadIdx.x >> 6;         // ntile 0..3
  const int fr = threadIdx.x & 15;
  const int fq = (threadIdx.x >> 4) & 3;
  const unsigned short* wb = Wt + ((wv * 16 + fr) * 64) + fq * 8;
  bf16x8 bh0 = *(const bf16x8*)(wb);
  bf16x8 bh1 = *(const bf16x8*)(wb + 32);
  bf16x8 bl0 = *(const bf16x8*)(wb + 4096);
  bf16x8 bl1 = *(const bf16x8*)(wb + 4096 + 32);
  uint2 ph = make_uint2(0u, 0u), pl = make_uint2(0u, 0u);
  if (node < n) {
    f32x4 xv =
        __builtin_nontemporal_load((const f32x4*)(x + (size_t)node * 64 + c4));
    unsigned int h0, l0, h1, l1, h2, l2, h3, l3;
    bsplit(xv.x, h0, l0);
    bsplit(xv.y, h1, l1);
    bsplit(xv.z, h2, l2);
    bsplit(xv.w, h3, l3);
    ph = make_uint2(h0 | (h1 << 16), h2 | (h3 << 16));
    pl = make_uint2(l0 | (l1 << 16), l2 | (l3 << 16));
  }
  *(uint2*)(&Ahi[r16][c4]) = ph;
  *(uint2*)(&Alo[r16][c4]) = pl;
  if ((threadIdx.x & 15) == 0) dvs[r16] = (node < n) ? dinv[node] : 0.f;
  __syncthreads();
  bf16x8 ah0 = *(const bf16x8*)(&Ahi[fr][fq * 8]);
  bf16x8 ah1 = *(const bf16x8*)(&Ahi[fr][fq * 8 + 32]);
  bf16x8 aL0 = *(const bf16x8*)(&Alo[fr][fq * 8]);
  bf16x8 aL1 = *(const bf16x8*)(&Alo[fr][fq * 8 + 32]);
  f32x4 acc = {0.f, 0.f, 0.f, 0.f};
  acc = __builtin_amdgcn_mfma_f32_16x16x32_bf16(ah0, bh0, acc, 0, 0, 0);
  acc = __builtin_amdgcn_mfma_f32_16x16x32_bf16(aL0, bh0, acc, 0, 0, 0);
  acc = __builtin_amdgcn_mfma_f32_16x16x32_bf16(ah0, bl0, acc, 0, 0, 0);
  acc = __builtin_amdgcn_mfma_f32_16x16x32_bf16(ah1, bh1, acc, 0, 0, 0);
  acc = __builtin_amdgcn_mfma_f32_16x16x32_bf16(aL1, bh1, acc, 0, 0, 0);
  acc = __builtin_amdgcn_mfma_f32_16x16x32_bf16(ah1, bl1, acc, 0, 0, 0);
  const int col = wv * 16 + fr;
#pragma unroll
  for (int j = 0; j < 4; ++j) {
    int row = fq * 4 + j;
    int nd = blockIdx.x * 16 + row;
    if (nd < n)
      hbf[(size_t)nd * 64 + col] = (unsigned short)bf16r(dvs[row] * acc[j]);
  }
}

// Fused layer 1->2: agg (64, relu, b) -> MFMA gemm (64->64) -> bf16.
// Gather: 16 lanes/node = 8 col-lanes x 2 neighbor-halves; 16 nodes/block.
// 8 rows in flight per 16-lane group (2 int4 idx + 8 uint4 row loads).
__global__ __launch_bounds__(BLOCK) void fused_agg_gemm64(
    const unsigned short* __restrict__ hin, const int* __restrict__ csr_src,
    const int* __restrict__ offs, const int* __restrict__ cnt,
    const float* __restrict__ dinv, const float* __restrict__ bias,
    const unsigned short* __restrict__ Wt, unsigned short* __restrict__ hout,
    int n) {
  __shared__ unsigned short Ahi[16][72];
  __shared__ unsigned short Alo[16][72];
  __shared__ float dvs[16];
  if (blockIdx.x == 0 && threadIdx.x < 8)  // zero dummy row for fused32
    *(uint4*)(hout + (size_t)n * 64 + threadIdx.x * 8) =
        make_uint4(0u, 0u, 0u, 0u);
  const int g = threadIdx.x >> 4;
  const int lane16 = threadIdx.x & 15;
  const int colgrp = lane16 & 7;
  const int half = lane16 >> 3;
  const int c8 = colgrp * 8;
  const int node = blockIdx.x * 16 + g;
  const bool valid = node < n;
  float dnode = 0.f;
  uint4 qh = make_uint4(0u, 0u, 0u, 0u), ql = make_uint4(0u, 0u, 0u, 0u);
  const char* hbase = (const char*)hin + c8 * 2;  // lane's 16B column slice
  if (valid) {
    const int start = offs[node];  // 4-aligned
    const int cn = cnt[node];
    const int* cp = csr_src + start;
    float4 l0 = make_float4(0.f, 0.f, 0.f, 0.f), h0 = l0;
    float4 l1 = l0, h1 = l0, l2 = l0, h2 = l0, l3 = l0, h3 = l0;
    if (half == 0)
      acc_bf8(l0, h0, *(const uint4*)(hbase + ((unsigned)node << 7)));  // self
    int j = half * 4;
    for (; j + 8 < cn; j += 16) {  // two 4-groups of this half in flight
      int4 sv0 = *(const int4*)(cp + j);
      int4 sv1 = *(const int4*)(cp + j + 8);
      uint4 u0 = *(const uint4*)(hbase + ((unsigned)sv0.x << 7));
      uint4 u1 = *(const uint4*)(hbase + ((unsigned)sv0.y << 7));
      uint4 u2 = *(const uint4*)(hbase + ((unsigned)sv0.z << 7));
      uint4 u3 = *(const uint4*)(hbase + ((unsigned)sv0.w << 7));
      uint4 u4 = *(const uint4*)(hbase + ((unsigned)sv1.x << 7));
      uint4 u5 = *(const uint4*)(hbase + ((unsigned)sv1.y << 7));
      uint4 u6 = *(const uint4*)(hbase + ((unsigned)sv1.z << 7));
      uint4 u7 = *(const uint4*)(hbase + ((unsigned)sv1.w << 7));
      acc_bf8(l0, h0, u0);
      acc_bf8(l1, h1, u1);
      acc_bf8(l2, h2, u2);
      acc_bf8(l3, h3, u3);
      acc_bf8(l0, h0, u4);
      acc_bf8(l1, h1, u5);
      acc_bf8(l2, h2, u6);
      acc_bf8(l3, h3, u7);
    }
    if (j < cn) {  // last 4-group of this half
      int4 sv = *(const int4*)(cp + j);
      uint4 u0 = *(const uint4*)(hbase + ((unsigned)sv.x << 7));
      uint4 u1 = *(const uint4*)(hbase + ((unsigned)sv.y << 7));
      uint4 u2 = *(const uint4*)(hbase + ((unsigned)sv.z << 7));
      uint4 u3 = *(const uint4*)(hbase + ((unsigned)sv.w << 7));
      acc_bf8(l0, h0, u0);
      acc_bf8(l1, h1, u1);
      acc_bf8(l2, h2, u2);
      acc_bf8(l3, h3, u3);
    }
    float4 alo = make_float4((l0.x + l1.x) + (l2.x + l3.x),
                             (l0.y + l1.y) + (l2.y + l3.y),
                             (l0.z + l1.z) + (l2.z + l3.z),
                             (l0.w + l1.w) + (l2.w + l3.w));
    float4 ahi = make_float4((h0.x + h1.x) + (h2.x + h3.x),
                             (h0.y + h1.y) + (h2.y + h3.y),
                             (h0.z + h1.z) + (h2.z + h3.z),
                             (h0.w + h1.w) + (h2.w + h3.w));
    alo.x += __shfl_xor(alo.x, 8); alo.y += __shfl_xor(alo.y, 8);
    alo.z += __shfl_xor(alo.z, 8); alo.w += __shfl_xor(alo.w, 8);
    ahi.x += __shfl_xor(ahi.x, 8); ahi.y += __shfl_xor(ahi.y, 8);
    ahi.z += __shfl_xor(ahi.z, 8); ahi.w += __shfl_xor(ahi.w, 8);
    dnode = dinv[node];
    if (half == 0) {
      float4 b4l = *(const float4*)(bias + c8);
      float4 b4h = *(const float4*)(bias + c8 + 4);
      float v0 = fmaxf(fmaf(dnode, alo.x, b4l.x), 0.f);
      float v1 = fmaxf(fmaf(dnode, alo.y, b4l.y), 0.f);
      float v2 = fmaxf(fmaf(dnode, alo.z, b4l.z), 0.f);
      float v3 = fmaxf(fmaf(dnode, alo.w, b4l.w), 0.f);
      float v4 = fmaxf(fmaf(dnode, ahi.x, b4h.x), 0.f);
      float v5 = fmaxf(fmaf(dnode, ahi.y, b4h.y), 0.f);
      float v6 = fmaxf(fmaf(dnode, ahi.z, b4h.z), 0.f);
      float v7 = fmaxf(fmaf(dnode, ahi.w, b4h.w), 0.f);
      unsigned int h0u, l0u, h1u, l1u, h2u, l2u, h3u, l3u;
      unsigned int h4u, l4u, h5u, l5u, h6u, l6u, h7u, l7u;
      bsplit(v0, h0u, l0u); bsplit(v1, h1u, l1u);
      bsplit(v2, h2u, l2u); bsplit(v3, h3u, l3u);
      bsplit(v4, h4u, l4u); bsplit(v5, h5u, l5u);
      bsplit(v6, h6u, l6u); bsplit(v7, h7u, l7u);
      qh = make_uint4(h0u | (h1u << 16), h2u | (h3u << 16),
                      h4u | (h5u << 16), h6u | (h7u << 16));
      ql = make_uint4(l0u | (l1u << 16), l2u | (l3u << 16),
                      l4u | (l5u << 16), l6u | (l7u << 16));
    }
  }
  if (half == 0) {
    *(uint4*)(&Ahi[g][c8]) = qh;
    *(uint4*)(&Alo[g][c8]) = ql;
    if (lane16 == 0) dvs[g] = dnode;
  }
  // B frags: issue before barrier so latency overlaps the sync.
  const int wv = threadIdx.x >> 6;
  const int fr = threadIdx.x & 15;
  const int fq = (threadIdx.x >> 4) & 3;
  const unsigned short* wb = Wt + ((wv * 16 + fr) * 64) + fq * 8;
  bf16x8 bh0 = *(const bf16x8*)(wb);
  bf16x8 bh1 = *(const bf16x8*)(wb + 32);
  bf16x8 bl0 = *(const bf16x8*)(wb + 4096);
  bf16x8 bl1 = *(const bf16x8*)(wb + 4096 + 32);
  __syncthreads();
  bf16x8 ah0 = *(const bf16x8*)(&Ahi[fr][fq * 8]);
  bf16x8 ah1 = *(const bf16x8*)(&Ahi[fr][fq * 8 + 32]);
  bf16x8 aL0 = *(const bf16x8*)(&Alo[fr][fq * 8]);
  bf16x8 aL1 = *(const bf16x8*)(&Alo[fr][fq * 8 + 32]);
  f32x4 acc = {0.f, 0.f, 0.f, 0.f};
  acc = __builtin_amdgcn_mfma_f32_16x16x32_bf16(ah0, bh0, acc, 0, 0, 0);
  acc = __builtin_amdgcn_mfma_f32_16x16x32_bf16(aL0, bh0, acc, 0, 0, 0);
  acc = __builtin_amdgcn_mfma_f32_16x16x32_bf16(ah0, bl0, acc, 0, 0, 0);
  acc = __builtin_amdgcn_mfma_f32_16x16x32_bf16(ah1, bh1, acc, 0, 0, 0);
  acc = __builtin_amdgcn_mfma_f32_16x16x32_bf16(aL1, bh1, acc, 0, 0, 0);
  acc = __builtin_amdgcn_mfma_f32_16x16x32_bf16(ah1, bl1, acc, 0, 0, 0);
  const int col = wv * 16 + fr;
#pragma unroll
  for (int j = 0; j < 4; ++j) {
    int row = fq * 4 + j;
    int nd = blockIdx.x * 16 + row;
    if (nd < n)
      hout[(size_t)nd * 64 + col] = (unsigned short)bf16r(dvs[row] * acc[j]);
  }
}

// Fused layer 2->3: agg (64, relu, b) -> MFMA gemm (64->32) -> bf16.
// Gather: 8 lanes/node, 32 nodes/block, 8 rows in flight.
__global__ __launch_bounds__(BLOCK) void fused_agg_gemm32(
    const unsigned short* __restrict__ hin, const int* __restrict__ csr_src,
    const int* __restrict__ offs, const int* __restrict__ cnt,
    const float* __restrict__ dinv, const float* __restrict__ bias,
    const unsigned short* __restrict__ Wt, unsigned short* __restrict__ hout,
    int n) {
  __shared__ unsigned short Ahi[32][72];
  __shared__ unsigned short Alo[32][72];
  __shared__ float dvs[32];
  if (blockIdx.x == 0 && threadIdx.x < 4)  // zero dummy 32-wide row for agg3
    *(uint4*)(hout + (size_t)n * 32 + threadIdx.x * 8) =
        make_uint4(0u, 0u, 0u, 0u);
  const int g = threadIdx.x >> 3;
  const int lane8 = threadIdx.x & 7;
  const int c8 = lane8 * 8;
  const int node = blockIdx.x * 32 + g;
  const bool valid = node < n;
  float dnode = 0.f;
  uint4 qh = make_uint4(0u, 0u, 0u, 0u), ql = make_uint4(0u, 0u, 0u, 0u);
  const char* hbase = (const char*)hin + c8 * 2;
  if (valid) {
    const int start = offs[node];  // 4-aligned
    const int cn = cnt[node];
    const int* cp = csr_src + start;
    float4 l0 = make_float4(0.f, 0.f, 0.f, 0.f), h0 = l0;
    float4 l1 = l0, h1 = l0, l2 = l0, h2 = l0, l3 = l0, h3 = l0;
    acc_bf8(l0, h0, *(const uint4*)(hbase + ((unsigned)node << 7)));
    int j = 0;
    for (; j + 4 < cn; j += 8) {  // two 4-groups in flight
      int4 sv0 = *(const int4*)(cp + j);
      int4 sv1 = *(const int4*)(cp + j + 4);
      uint4 u0 = *(const uint4*)(hbase + ((unsigned)sv0.x << 7));
      uint4 u1 = *(const uint4*)(hbase + ((unsigned)sv0.y << 7));
      uint4 u2 = *(const uint4*)(hbase + ((unsigned)sv0.z << 7));
      uint4 u3 = *(const uint4*)(hbase + ((unsigned)sv0.w << 7));
      uint4 u4 = *(const uint4*)(hbase + ((unsigned)sv1.x << 7));
      uint4 u5 = *(const uint4*)(hbase + ((unsigned)sv1.y << 7));
      uint4 u6 = *(const uint4*)(hbase + ((unsigned)sv1.z << 7));
      uint4 u7 = *(const uint4*)(hbase + ((unsigned)sv1.w << 7));
      acc_bf8(l0, h0, u0);
      acc_bf8(l1, h1, u1);
      acc_bf8(l2, h2, u2);
      acc_bf8(l3, h3, u3);
      acc_bf8(l0, h0, u4);
      acc_bf8(l1, h1, u5);
      acc_bf8(l2, h2, u6);
      acc_bf8(l3, h3, u7);
    }
    if (j < cn) {
      int4 sv = *(const int4*)(cp + j);
      uint4 u0 = *(const uint4*)(hbase + ((unsigned)sv.x << 7));
      uint4 u1 = *(const uint4*)(hbase + ((unsigned)sv.y << 7));
      uint4 u2 = *(const uint4*)(hbase + ((unsigned)sv.z << 7));
      uint4 u3 = *(const uint4*)(hbase + ((unsigned)sv.w << 7));
      acc_bf8(l0, h0, u0);
      acc_bf8(l1, h1, u1);
      acc_bf8(l2, h2, u2);
      acc_bf8(l3, h3, u3);
    }
    float4 alo = make_float4((l0.x + l1.x) + (l2.x + l3.x),
                             (l0.y + l1.y) + (l2.y + l3.y),
                             (l0.z + l1.z) + (l2.z + l3.z),
                             (l0.w + l1.w) + (l2.w + l3.w));
    float4 ahi = make_float4((h0.x + h1.x) + (h2.x + h3.x),
                             (h0.y + h1.y) + (h2.y + h3.y),
                             (h0.z + h1.z) + (h2.z + h3.z),
                             (h0.w + h1.w) + (h2.w + h3.w));
    dnode = dinv[node];
    float4 b4l = *(const float4*)(bias + c8);
    float4 b4h = *(const float4*)(bias + c8 + 4);
    float v0 = fmaxf(fmaf(dnode, alo.x, b4l.x), 0.f);
    float v1 = fmaxf(fmaf(dnode, alo.y, b4l.y), 0.f);
    float v2 = fmaxf(fmaf(dnode, alo.z, b4l.z), 0.f);
    float v3 = fmaxf(fmaf(dnode, alo.w, b4l.w), 0.f);
    float v4 = fmaxf(fmaf(dnode, ahi.x, b4h.x), 0.f);
    float v5 = fmaxf(fmaf(dnode, ahi.y, b4h.y), 0.f);
    float v6 = fmaxf(fmaf(dnode, ahi.z, b4h.z), 0.f);
    float v7 = fmaxf(fmaf(dnode, ahi.w, b4h.w), 0.f);
    unsigned int h0u, l0u, h1u, l1u, h2u, l2u, h3u, l3u;
    unsigned int h4u, l4u, h5u, l5u, h6u, l6u, h7u, l7u;
    bsplit(v0, h0u, l0u); bsplit(v1, h1u, l1u);
    bsplit(v2, h2u, l2u); bsplit(v3, h3u, l3u);
    bsplit(v4, h4u, l4u); bsplit(v5, h5u, l5u);
    bsplit(v6, h6u, l6u); bsplit(v7, h7u, l7u);
    qh = make_uint4(h0u | (h1u << 16), h2u | (h3u << 16),
                    h4u | (h5u << 16), h6u | (h7u << 16));
    ql = make_uint4(l0u | (l1u << 16), l2u | (l3u << 16),
                    l4u | (l5u << 16), l6u | (l7u << 16));
  }
  *(uint4*)(&Ahi[g][c8]) = qh;
  *(uint4*)(&Alo[g][c8]) = ql;
  if (lane8 == 0) dvs[g] = dnode;
  const int wv = threadIdx.x >> 6;
  const int mt = wv >> 1;   // m-tile 0..1
  const int nt = wv & 1;    // n-tile 0..1
  const int fr = threadIdx.x & 15;
  const int fq = (threadIdx.x >> 4) & 3;
  const unsigned short* wb = Wt + ((nt * 16 + fr) * 64) + fq * 8;
  bf16x8 bh0 = *(const bf16x8*)(wb);
  bf16x8 bh1 = *(const bf16x8*)(wb + 32);
  bf16x8 bl0 = *(const bf16x8*)(wb + 2048);
  bf16x8 bl1 = *(const bf16x8*)(wb + 2048 + 32);
  __syncthreads();
  bf16x8 ah0 = *(const bf16x8*)(&Ahi[mt * 16 + fr][fq * 8]);
  bf16x8 ah1 = *(const bf16x8*)(&Ahi[mt * 16 + fr][fq * 8 + 32]);
  bf16x8 aL0 = *(const bf16x8*)(&Alo[mt * 16 + fr][fq * 8]);
  bf16x8 aL1 = *(const bf16x8*)(&Alo[mt * 16 + fr][fq * 8 + 32]);
  f32x4 acc = {0.f, 0.f, 0.f, 0.f};
  acc = __builtin_amdgcn_mfma_f32_16x16x32_bf16(ah0, bh0, acc, 0, 0, 0);
  acc = __builtin_amdgcn_mfma_f32_16x16x32_bf16(aL0, bh0, acc, 0, 0, 0);
  acc = __builtin_amdgcn_mfma_f32_16x16x32_bf16(ah0, bl0, acc, 0, 0, 0);
  acc = __builtin_amdgcn_mfma_f32_16x16x32_bf16(ah1, bh1, acc, 0, 0, 0);
  acc = __builtin_amdgcn_mfma_f32_16x16x32_bf16(aL1, bh1, acc, 0, 0, 0);
  acc = __builtin_amdgcn_mfma_f32_16x16x32_bf16(ah1, bl1, acc, 0, 0, 0);
  const int col = nt * 16 + fr;
#pragma unroll
  for (int j = 0; j < 4; ++j) {
    int row = mt * 16 + fq * 4 + j;
    int nd = blockIdx.x * 32 + row;
    if (nd < n)
      hout[(size_t)nd * 32 + col] = (unsigned short)bf16r(dvs[row] * acc[j]);
  }
}

// Final aggregation (F=32, no relu): 4 lanes/node, 64 nodes/block,
// 8 rows in flight.
__global__ __launch_bounds__(BLOCK) void agg3_kernel(
    const unsigned short* __restrict__ hbf, const int* __restrict__ csr_src,
    const int* __restrict__ offs, const int* __restrict__ cnt,
    const float* __restrict__ dinv, const float* __restrict__ bias,
    float* __restrict__ out, int n) {
  constexpr int F = 32;
  const int node = blockIdx.x * 64 + (int)(threadIdx.x >> 2);
  const int c8 = (threadIdx.x & 3) * 8;
  if (node >= n) return;
  const int start = offs[node];  // 4-aligned
  const int cn = cnt[node];
  const int* cp = csr_src + start;
  const char* hbase = (const char*)hbf + c8 * 2;
  float4 l0 = make_float4(0.f, 0.f, 0.f, 0.f), h0 = l0;
  float4 l1 = l0, h1 = l0, l2 = l0, h2 = l0, l3 = l0, h3 = l0;
  acc_bf8(l0, h0, *(const uint4*)(hbase + ((unsigned)node << 6)));
  int j = 0;
  for (; j + 4 < cn; j += 8) {  // two 4-groups in flight
    int4 sv0 = *(const int4*)(cp + j);
    int4 sv1 = *(const int4*)(cp + j + 4);
    uint4 u0 = *(const uint4*)(hbase + ((unsigned)sv0.x << 6));
    uint4 u1 = *(const uint4*)(hbase + ((unsigned)sv0.y << 6));
    uint4 u2 = *(const uint4*)(hbase + ((unsigned)sv0.z << 6));
    uint4 u3 = *(const uint4*)(hbase + ((unsigned)sv0.w << 6));
    uint4 u4 = *(const uint4*)(hbase + ((unsigned)sv1.x << 6));
    uint4 u5 = *(const uint4*)(hbase + ((unsigned)sv1.y << 6));
    uint4 u6 = *(const uint4*)(hbase + ((unsigned)sv1.z << 6));
    uint4 u7 = *(const uint4*)(hbase + ((unsigned)sv1.w << 6));
    acc_bf8(l0, h0, u0);
    acc_bf8(l1, h1, u1);
    acc_bf8(l2, h2, u2);
    acc_bf8(l3, h3, u3);
    acc_bf8(l0, h0, u4);
    acc_bf8(l1, h1, u5);
    acc_bf8(l2, h2, u6);
    acc_bf8(l3, h3, u7);
  }
  if (j < cn) {
    int4 sv = *(const int4*)(cp + j);
    uint4 u0 = *(const uint4*)(hbase + ((unsigned)sv.x << 6));
    uint4 u1 = *(const uint4*)(hbase + ((unsigned)sv.y << 6));
    uint4 u2 = *(const uint4*)(hbase + ((unsigned)sv.z << 6));
    uint4 u3 = *(const uint4*)(hbase + ((unsigned)sv.w << 6));
    acc_bf8(l0, h0, u0);
    acc_bf8(l1, h1, u1);
    acc_bf8(l2, h2, u2);
    acc_bf8(l3, h3, u3);
  }
  float4 alo = make_float4((l0.x + l1.x) + (l2.x + l3.x),
                           (l0.y + l1.y) + (l2.y + l3.y),
                           (l0.z + l1.z) + (l2.z + l3.z),
                           (l0.w + l1.w) + (l2.w + l3.w));
  float4 ahi = make_float4((h0.x + h1.x) + (h2.x + h3.x),
                           (h0.y + h1.y) + (h2.y + h3.y),
                           (h0.z + h1.z) + (h2.z + h3.z),
                           (h0.w + h1.w) + (h2.w + h3.w));
  float d = dinv[node];
  float4 blo = *(const float4*)(bias + c8);
  float4 bhi = *(const float4*)(bias + c8 + 4);
  f32x4 vlo = {fmaf(d, alo.x, blo.x), fmaf(d, alo.y, blo.y),
               fmaf(d, alo.z, blo.z), fmaf(d, alo.w, blo.w)};
  f32x4 vhi = {fmaf(d, ahi.x, bhi.x), fmaf(d, ahi.y, bhi.y),
               fmaf(d, ahi.z, bhi.z), fmaf(d, ahi.w, bhi.w)};
  float* op = out + (size_t)node * F + c8;
  __builtin_nontemporal_store(vlo, (f32x4*)op);
  __builtin_nontemporal_store(vhi, (f32x4*)(op + 4));
}

static inline size_t align_up(size_t v, size_t a) { return (v + a - 1) & ~(a - 1); }

extern "C" void kernel_launch(void* const* d_in, const int* in_sizes, int n_in,
                              void* d_out, int out_size, void* d_ws, size_t ws_size,
                              hipStream_t stream) {
  const float* x = (const float*)d_in[0];
  const int* edge_index = (const int*)d_in[1];
  const float* W1 = (const float*)d_in[2];
  const float* b1 = (const float*)d_in[3];
  const float* W2 = (const float*)d_in[4];
  const float* b2 = (const float*)d_in[5];
  const float* W3 = (const float*)d_in[6];
  const float* b3 = (const float*)d_in[7];
  float* out = (float*)d_out;

  const int n = in_sizes[0] / 64;       // 100000
  const int e = in_sizes[1] / 2;        // 1600000
  const int* e_src = edge_index;
  const int* e_dst = edge_index + e;
  const int npb = (n + NBUCKET - 1) / NBUCKET;  // 196

  char* ws = (char*)d_ws;
  size_t off = 0;
  int* bcursor = (int*)(ws + off); off = align_up(off + NBUCKET * 4, 512);
  int* offs    = (int*)(ws + off); off = align_up(off + (size_t)n * 4, 512);
  int* cnt     = (int*)(ws + off); off = align_up(off + (size_t)n * 4, 512);
  float* dinv  = (float*)(ws + off); off = align_up(off + (size_t)n * 4, 512);
  int* binned  = (int*)(ws + off); off = align_up(off + (size_t)NBUCKET * SLOT * 4, 512);
  int* csr_src = (int*)(ws + off); off = align_up(off + (size_t)NBUCKET * SLOT * 4, 512);
  unsigned short* hbuf_a = (unsigned short*)(ws + off);
  off = align_up(off + (size_t)(n + 1) * 64 * 2, 512);  // +1 dummy row
  unsigned short* hbuf_b = (unsigned short*)(ws + off);
  off = align_up(off + (size_t)(n + 1) * 64 * 2, 512);  // +1 dummy row
  unsigned short* Wt = (unsigned short*)(ws + off);
  off = align_up(off + (size_t)20480 * 2, 512);
  (void)ws_size;

  unsigned short* Wt1 = Wt;            // 64x64 hi/lo
  unsigned short* Wt2 = Wt + 8192;     // 64x64 hi/lo
  unsigned short* Wt3 = Wt + 16384;    // 32x64 hi/lo

  const int gC = (e + CHUNK - 1) / CHUNK;

  hipMemsetAsync(bcursor, 0, NBUCKET * 4, stream);
  binning_kernel<<<gC, BLOCK, 0, stream>>>(e_src, e_dst, bcursor, binned, W1,
                                           W2, W3, Wt, e, npb);
  bucket_build<<<NBUCKET, BLOCK, 0, stream>>>(binned, bcursor, offs, cnt, dinv,
                                              csr_src, n, npb);

  gemm1_kernel<<<(n + 15) / 16, BLOCK, 0, stream>>>(x, Wt1, dinv, hbuf_a, n);
  fused_agg_gemm64<<<(n + 15) / 16, BLOCK, 0, stream>>>(
      hbuf_a, csr_src, offs, cnt, dinv, b1, Wt2, hbuf_b, n);
  fused_agg_gemm32<<<(n + 31) / 32, BLOCK, 0, stream>>>(
      hbuf_b, csr_src, offs, cnt, dinv, b2, Wt3, hbuf_a, n);
  agg3_kernel<<<(n + 63) / 64, BLOCK, 0, stream>>>(hbuf_a, csr_src, offs, cnt,
                                                   dinv, b3, out, n);
}